// Round 4
// baseline (126.605 us; speedup 1.0000x reference)
//
#include <hip/hip_runtime.h>

// Problem constants (PointPillarsScatter)
#define NB 4
#define NC 64
#define NH 282
#define NW 282
#define NP 12000
#define HWC (NH * NW)          // 79524, divisible by 4
#define QHW (HWC / 4)          // 19881 int4/float4 per channel plane
#define CLAIM_INTS (NB * HWC)  // 318096 ints = 1.27 MB
#define SPLIT 8                // workgroups per (b,c) plane in fill

// Claim map in a device global (known-good from r3).
__device__ __align__(16) int g_claim[CLAIM_INTS];

// Pass 0: claim = -1 everywhere (vectorized int4 stores).
__global__ void pps_init_kernel() {
    int gid = blockIdx.x * blockDim.x + threadIdx.x;
    if (gid < CLAIM_INTS / 4) {
        ((int4*)g_claim)[gid] = make_int4(-1, -1, -1, -1);
    }
}

// Pass 1: each valid point claims its cell with atomicMax(point index).
// Last-write-wins == highest p wins. Grid index bit-matches the XLA:CPU
// golden: XLA rewrites /0.16 into *(1/0.16f) == *6.25f exactly (r3: absmax=0).
__global__ void pps_claim_kernel(const float* __restrict__ pfn_in) {
    int gid = blockIdx.x * blockDim.x + threadIdx.x;
    if (gid >= NB * NP) return;
    int b = gid / NP;
    int p = gid - b * NP;
    const float* base = pfn_in + (size_t)b * 2 * NP;  // [b][2][P][1]
    float x = base[p];
    if (x == 0.0f) return;                      // invalid -> OOB in ref -> dropped
    float y = base[NP + p];
    int xg = (int)floorf((x + 22.0f) * 6.25f);
    int yg = (int)floorf((y + 22.0f) * 6.25f);
    xg = min(max(xg, 0), NW - 1);
    yg = min(max(yg, 0), NH - 1);
    atomicMax(&g_claim[b * HWC + yg * NW + xg], p);
}

// Pass 2 (v2): LDS-staged gather fill.
// One workgroup owns 1/SPLIT of one (b,c) plane; the full 48 KB feature row
// PFN_output[b][c][:] is staged in LDS so the 4 random gathers per output
// float4 hit LDS (~69 TB/s, conflict factor ~2x) instead of thrashing
// L1 (48 KB row > 32 KB L1) and burning L2 BW on 64 B line amplification.
// Global side is then fully coalesced: staged row reads + claim int4 reads
// (L2-hot, 1.27 MB unique) + the mandatory 81.4 MB float4 output write.
__global__ __launch_bounds__(256) void pps_fill2_kernel(
        const float* __restrict__ pfn_out, float4* __restrict__ out) {
    __shared__ float row[NP];            // 46.9 KB -> 3 workgroups/CU
    int wg = blockIdx.x;
    int s = wg & (SPLIT - 1);
    int plane = wg / SPLIT;              // b*NC + c
    int b = plane >> 6;                  // NC == 64

    // Stage the feature row: 3000 coalesced float4 loads.
    const float4* src4 = (const float4*)(pfn_out + (size_t)plane * NP);
    for (int i = threadIdx.x; i < NP / 4; i += 256) {
        ((float4*)row)[i] = src4[i];
    }
    __syncthreads();

    const int4* cl = (const int4*)(g_claim + (size_t)b * HWC);
    float4* dst = out + (size_t)plane * QHW;
    const int chunk = (QHW + SPLIT - 1) / SPLIT;   // 2486
    int q0 = s * chunk;
    int q1 = min(q0 + chunk, QHW);
    for (int q = q0 + (int)threadIdx.x; q < q1; q += 256) {
        int4 c4 = cl[q];
        float4 v;
        v.x = (c4.x >= 0) ? row[c4.x] : 0.0f;
        v.y = (c4.y >= 0) ? row[c4.y] : 0.0f;
        v.z = (c4.z >= 0) ? row[c4.z] : 0.0f;
        v.w = (c4.w >= 0) ? row[c4.w] : 0.0f;
        dst[q] = v;
    }
}

extern "C" void kernel_launch(void* const* d_in, const int* in_sizes, int n_in,
                              void* d_out, int out_size, void* d_ws, size_t ws_size,
                              hipStream_t stream) {
    const float* pfn_in  = (const float*)d_in[0];   // (4, 2, 12000, 1) f32
    const float* pfn_out = (const float*)d_in[1];   // (4, 64, 12000)   f32
    float* out = (float*)d_out;                     // (4, 64, 282, 282) f32
    (void)d_ws; (void)ws_size;

    {
        int total = CLAIM_INTS / 4;      // 79524 int4 stores
        int threads = 256;
        pps_init_kernel<<<(total + threads - 1) / threads, threads, 0, stream>>>();
    }
    {
        int total = NB * NP;             // 48000 points
        int threads = 256;
        pps_claim_kernel<<<(total + threads - 1) / threads, threads, 0, stream>>>(pfn_in);
    }
    {
        int blocks = NB * NC * SPLIT;    // 2048 workgroups
        pps_fill2_kernel<<<blocks, 256, 0, stream>>>(pfn_out, (float4*)out);
    }
}